// Round 21
// baseline (335.531 us; speedup 1.0000x reference)
//
#include <hip/hip_runtime.h>

typedef short bf16x8 __attribute__((ext_vector_type(8)));
typedef short bf16x4 __attribute__((ext_vector_type(4)));
typedef float f32x4 __attribute__((ext_vector_type(4)));

#define MFMA16(a, b, c) __builtin_amdgcn_mfma_f32_16x16x32_bf16(a, b, c, 0, 0, 0)

// K=16 bf16 mfma: device pass has the builtin; host pass only needs to parse.
#if defined(__HIP_DEVICE_COMPILE__)
#define MFMAK16(a, b, c) __builtin_amdgcn_mfma_f32_16x16x16bf16_1k(a, b, c, 0, 0, 0)
#else
#define MFMAK16(a, b, c) (c)
#endif

__device__ __forceinline__ short f2bf(float x) {
  unsigned u = __builtin_bit_cast(unsigned, x);
  u += 0x7fffu + ((u >> 16) & 1u);
  return (short)(u >> 16);
}

// async global->LDS, 16B per lane; LDS dest must be wave-uniform base (HW adds lane*16)
__device__ __forceinline__ void gload16(const void* g, void* l) {
  __builtin_amdgcn_global_load_lds((const __attribute__((address_space(1))) void*)g,
                                   (__attribute__((address_space(3))) void*)l, 16, 0, 0);
}

// ---- problem constants ----
#define BB 16
#define SS 4096
#define CC 640
#define TT 77
#define NHH 8
#define HDD 80
#define DP 96
#define MM (BB * SS)

// ================= K0a: weight transpose + bf16 convert (wq, wo, wk, wv) =========
__global__ __launch_bounds__(256) void k_wt(const float* __restrict__ wq,
                                            const float* __restrict__ wo,
                                            const float* __restrict__ wk,
                                            const float* __restrict__ wv,
                                            short* __restrict__ wqT,
                                            short* __restrict__ woT,
                                            short* __restrict__ wkT,
                                            short* __restrict__ wvT) {
  int z = blockIdx.z;
  const float* src = (z == 0) ? wq : (z == 1) ? wo : (z == 2) ? wk : wv;
  short* dst = (z == 0) ? wqT : (z == 1) ? woT : (z == 2) ? wkT : wvT;
  int R = (z < 2) ? 640 : 768;
  int r0 = blockIdx.y * 64;
  if (r0 >= R) return;
  int o0 = blockIdx.x * 64;
  __shared__ float t[64][65];
  int tx = threadIdx.x & 63, ty = threadIdx.x >> 6;
#pragma unroll
  for (int it = 0; it < 16; ++it) {
    int rr = it * 4 + ty;
    t[tx][rr] = src[(size_t)(r0 + rr) * 640 + o0 + tx];
  }
  __syncthreads();
#pragma unroll
  for (int it = 0; it < 16; ++it) {
    int orow = it * 4 + ty;
    dst[(size_t)(o0 + orow) * R + r0 + tx] = f2bf(t[orow][tx]);
  }
}

// ================= K0b: enc -> bf16 [1280][768] (rows >=1232 zeroed) ===========
__global__ __launch_bounds__(256) void k_enc(const float* __restrict__ enc,
                                             short* __restrict__ encb) {
  int idx = (blockIdx.x * 256 + threadIdx.x) * 8;  // 8 shorts, same row (768%8==0)
  int row = idx / 768;
  bf16x8 o = {};
  if (row < 1232) {
    const float* p = enc + (size_t)row * 768 + (idx % 768);
    float4 a0 = *(const float4*)p;
    float4 a1 = *(const float4*)(p + 4);
    o[0] = f2bf(a0.x); o[1] = f2bf(a0.y); o[2] = f2bf(a0.z); o[3] = f2bf(a0.w);
    o[4] = f2bf(a1.x); o[5] = f2bf(a1.y); o[6] = f2bf(a1.z); o[7] = f2bf(a1.w);
  }
  *(bf16x8*)(encb + idx) = o;
}

// ================= K0c: K/V projection as m97-style GEMM =================
// M = 1280 (16b x 77t padded), N = 1280 (K | V), K = 768. (R18 version)
__global__ __launch_bounds__(256) void k_kv2(const short* __restrict__ encb,
                                             const short* __restrict__ wkT,
                                             const short* __restrict__ wvT,
                                             short* __restrict__ kb,
                                             short* __restrict__ vb) {
  int n0 = blockIdx.x * 128;
  int m0 = blockIdx.y * 128;
  __shared__ short sA[2 * 128 * 32];
  __shared__ short sB[2 * 128 * 32];
  int w = threadIdx.x >> 6, lane = threadIdx.x & 63;
  int col = lane & 15, quad = lane >> 4;
  int wm = w & 1, wn = w >> 1;
  int ldrow = lane >> 2;
  int ldoff = (lane & 3) * 8;
  bool isV = (n0 >= 640);
  const short* wsrc = isV ? (wvT + (size_t)(n0 - 640) * 768) : (wkT + (size_t)n0 * 768);
  const short* gA0 = encb + (size_t)(m0 + w * 32 + ldrow) * 768 + ldoff;
  const short* gA1 = gA0 + 16 * 768;
  const short* gB0 = wsrc + (size_t)(w * 32 + ldrow) * 768 + ldoff;
  const short* gB1 = gB0 + 16 * 768;
  short* lA0 = sA + (w * 32) * 32;  // wave-uniform
  short* lA1 = lA0 + 16 * 32;
  short* lB0 = sB + (w * 32) * 32;
  short* lB1 = lB0 + 16 * 32;
  f32x4 acc[4][4] = {};
  gload16(gA0, lA0);
  gload16(gA1, lA1);
  gload16(gB0, lB0);
  gload16(gB1, lB1);
  for (int k0 = 0; k0 < 768; k0 += 32) {
    int cur = ((k0 >> 5) & 1) << 12;  // 0 or 4096 shorts
    if (k0 + 32 < 768) {
      int nxt = cur ^ 4096;
      gload16(gA0 + k0 + 32, lA0 + nxt);
      gload16(gA1 + k0 + 32, lA1 + nxt);
      gload16(gB0 + k0 + 32, lB0 + nxt);
      gload16(gB1 + k0 + 32, lB1 + nxt);
      asm volatile("s_waitcnt vmcnt(4)" ::: "memory");
    } else {
      asm volatile("s_waitcnt vmcnt(0)" ::: "memory");
    }
    __builtin_amdgcn_s_barrier();
    bf16x8 a[4], bb[4];
#pragma unroll
    for (int mt = 0; mt < 4; ++mt)
      a[mt] = *(const bf16x8*)(sA + cur + (wm * 64 + mt * 16 + col) * 32 + quad * 8);
#pragma unroll
    for (int nt = 0; nt < 4; ++nt)
      bb[nt] = *(const bf16x8*)(sB + cur + (wn * 64 + nt * 16 + col) * 32 + quad * 8);
    asm volatile("s_waitcnt lgkmcnt(0)" ::: "memory");
    __builtin_amdgcn_sched_barrier(0);
    __builtin_amdgcn_s_barrier();
#pragma unroll
    for (int mt = 0; mt < 4; ++mt)
#pragma unroll
      for (int nt = 0; nt < 4; ++nt)
        acc[mt][nt] = MFMA16(a[mt], bb[nt], acc[mt][nt]);
  }
  float scale = isV ? 1.f : 0.11180339887498949f;
#pragma unroll
  for (int mt = 0; mt < 4; ++mt)
#pragma unroll
    for (int nt = 0; nt < 4; ++nt) {
      int i = n0 + wn * 64 + nt * 16 + col;      // global 0..1279
      int j = isV ? (i - 640) : i;               // 0..639
      int h = j / 80, d = j % 80;
#pragma unroll
      for (int r = 0; r < 4; ++r) {
        int m = m0 + wm * 64 + mt * 16 + quad * 4 + r;
        if (m >= 1232) continue;
        int b = m / 77;
        int t = m - b * 77;
        float v = acc[mt][nt][r] * scale;
        if (isV)
          vb[(((size_t)(b * NHH + h) * 80 + d) * DP) + t] = f2bf(v);
        else
          kb[(((size_t)(b * NHH + h) * 80 + t) * DP) + d] = f2bf(v);
      }
    }
}

// ================= K1: fused LN, ONE-PASS (hs cached in f32 registers) =========
__global__ __launch_bounds__(512) void k_ln(const float* __restrict__ hs,
                                            const float* __restrict__ lnw,
                                            const float* __restrict__ lnb,
                                            short* __restrict__ xn) {
  int b = blockIdx.x >> 6;
  int s0 = (blockIdx.x & 63) * 64;
  int t = threadIdx.x;
  int sq = t & 15, cg = t >> 4;  // sq: s-quad, cg: c-group 0..31
  int s4 = sq * 4;
  const float* base = hs + (size_t)b * CC * SS + s0;
  f32x4 v[20];
  f32x4 sum = {}, sqs = {};
#pragma unroll
  for (int m = 0; m < 20; ++m) {
    int c = cg + m * 32;
    v[m] = *(const f32x4*)(base + (size_t)c * SS + s4);
    sum += v[m];
    sqs += v[m] * v[m];
  }
  __shared__ f32x4 redS[32][16];
  __shared__ f32x4 redQ[32][16];
  __shared__ float smu[64], srs[64];
  redS[cg][sq] = sum;
  redQ[cg][sq] = sqs;
  __syncthreads();
  if (t < 64) {
    int q = t >> 2, j = t & 3;
    float s = 0.f, qq = 0.f;
#pragma unroll
    for (int g = 0; g < 32; ++g) { s += redS[g][q][j]; qq += redQ[g][q][j]; }
    float mu = s * (1.f / 640.f);
    float var = qq * (1.f / 640.f) - mu * mu;
    smu[t] = mu;
    srs[t] = rsqrtf(var + 1e-6f);
  }
  __syncthreads();
  float mu[4], rs[4];
#pragma unroll
  for (int j = 0; j < 4; ++j) { mu[j] = smu[s4 + j]; rs[j] = srs[s4 + j]; }
  __shared__ short tq[64][80];  // 160B rows, 16B-aligned
  short* xrow = xn + (size_t)(b * SS + s0) * 640;
#pragma unroll
  for (int ch = 0; ch < 10; ++ch) {  // full unroll: v[] indices stay compile-time
    int c0 = ch * 64;
    if (ch) __syncthreads();
#pragma unroll
    for (int h = 0; h < 2; ++h) {
      int m = ch * 2 + h;
      int c = c0 + h * 32 + cg;
      float w = lnw[c], bb = lnb[c];
#pragma unroll
      for (int j = 0; j < 4; ++j)
        tq[s4 + j][h * 32 + cg] = f2bf((v[m][j] - mu[j]) * rs[j] * w + bb);
    }
    __syncthreads();
    {
      int s = t >> 3, g = t & 7;  // 512 thr cover 64 rows x 64 c in one shot
      uint4 x = *(const uint4*)&tq[s][g * 8];
      *(uint4*)(xrow + (size_t)s * 640 + c0 + g * 8) = x;
    }
  }
}

// ================= K2+K3 fused: Q projection + attention (R20 + light swizzle) ===
// 1D grid 2048, XCD-clustered (R19-verified FETCH win). Body = R14 proven version
// + BK=32 light XOR swizzle (unbundled from R19): stage source slot
// (lane&3)^(ldrow&3), read slot quad^(col&3). All rows == key mod 4 on both
// sides (offsets are multiples of 16/48/80) -> exact round-trip, VGPR-neutral.
// 8-way LDS conflict -> ~4-way (m136: 2.94x -> 1.58x).
__global__ __launch_bounds__(256) void k_qa(const short* __restrict__ xn,
                                            const short* __restrict__ wqT,
                                            const short* __restrict__ kb,
                                            const short* __restrict__ vb,
                                            short* __restrict__ qws) {
  int f = blockIdx.x;
  int xcd = f & 7;
  int i = f >> 3;                 // 0..255
  int s0 = (xcd * 64 + (i >> 2)) * 128;
  int pair = i & 3;
  int b = s0 >> 12;
  int t = threadIdx.x;
  int w = t >> 6, lane = t & 63;
  int col = lane & 15, quad = lane >> 4;
  int wm = w & 1, wh = w >> 1;
  int head = pair * 2 + wh;

  __shared__ short smem[4 * 64 * 104];  // 26624 shorts = 53248 B
  short* lA = smem;           // [2][128][32]
  short* lB = smem + 8192;    // [2][160][32]

  int ldrow = lane >> 2;
  int ldoff = ((lane & 3) ^ (ldrow & 3)) * 8;  // pre-swizzled source slot
  const short* gA = xn + (size_t)(s0 + w * 32 + ldrow) * 640 + ldoff;
  int browbase = (w < 2) ? w * 48 : 96 + (w - 2) * 32;
  const short* gB = wqT + (size_t)(pair * 160 + browbase + ldrow) * 640 + ldoff;
  short* lAw = lA + (w * 32) * 32;
  short* lBw = lB + browbase * 32;

  f32x4 acc[4][5] = {};
  gload16(gA, lAw);
  gload16(gA + 16 * 640, lAw + 16 * 32);
  if (w < 2) {
    gload16(gB, lBw);
    gload16(gB + 16 * 640, lBw + 16 * 32);
    gload16(gB + 32 * 640, lBw + 32 * 32);
  } else {
    gload16(gB, lBw);
    gload16(gB + 16 * 640, lBw + 16 * 32);
  }
  int so = (quad ^ (col & 3)) * 8;  // read-side swizzled slot
  for (int k0 = 0; k0 < 640; k0 += 32) {
    int coA = (k0 & 32) * 128;
    int coB = (k0 & 32) * 160;
    if (k0 + 32 < 640) {
      int nxA = coA ^ 4096;
      int nxB = coB ^ 5120;
      gload16(gA + k0 + 32, lAw + nxA);
      gload16(gA + 16 * 640 + k0 + 32, lAw + nxA + 16 * 32);
      if (w < 2) {
        gload16(gB + k0 + 32, lBw + nxB);
        gload16(gB + 16 * 640 + k0 + 32, lBw + nxB + 16 * 32);
        gload16(gB + 32 * 640 + k0 + 32, lBw + nxB + 32 * 32);
        asm volatile("s_waitcnt vmcnt(5)" ::: "memory");
      } else {
        gload16(gB + k0 + 32, lBw + nxB);
        gload16(gB + 16 * 640 + k0 + 32, lBw + nxB + 16 * 32);
        asm volatile("s_waitcnt vmcnt(4)" ::: "memory");
      }
    } else {
      asm volatile("s_waitcnt vmcnt(0)" ::: "memory");
    }
    __builtin_amdgcn_s_barrier();
    bf16x8 a[4], bb[5];
#pragma unroll
    for (int mt = 0; mt < 4; ++mt)
      a[mt] = *(const bf16x8*)(lA + coA + (wm * 64 + mt * 16 + col) * 32 + so);
#pragma unroll
    for (int nt = 0; nt < 5; ++nt)
      bb[nt] = *(const bf16x8*)(lB + coB + (wh * 80 + nt * 16 + col) * 32 + so);
    asm volatile("s_waitcnt lgkmcnt(0)" ::: "memory");
    __builtin_amdgcn_sched_barrier(0);
    __builtin_amdgcn_s_barrier();
#pragma unroll
    for (int mt = 0; mt < 4; ++mt)
#pragma unroll
      for (int nt = 0; nt < 5; ++nt)
        acc[mt][nt] = MFMA16(a[mt], bb[nt], acc[mt][nt]);
  }

  short* ql = smem + w * 6656;
  {
    uint4 z = {0u, 0u, 0u, 0u};
    *(uint4*)&ql[lane * 104 + 80] = z;
    *(uint4*)&ql[lane * 104 + 88] = z;
  }
#pragma unroll
  for (int mt = 0; mt < 4; ++mt)
#pragma unroll
    for (int nt = 0; nt < 5; ++nt)
#pragma unroll
      for (int r = 0; r < 4; ++r)
        ql[(mt * 16 + quad * 4 + r) * 104 + nt * 16 + col] = f2bf(acc[mt][nt][r]);

  const short* kbase = kb + (size_t)(b * NHH + head) * 80 * DP;
  const short* vbase = vb + (size_t)(b * NHH + head) * 80 * DP;
  int kq = quad * 8;
#pragma unroll 1
  for (int sg = 0; sg < 4; ++sg) {
    f32x4 sc[5] = {};
#pragma unroll
    for (int ks = 0; ks < 3; ++ks) {
      int kk = ks * 32 + kq;
      bf16x8 aq = *(const bf16x8*)&ql[(sg * 16 + col) * 104 + kk];
#pragma unroll
      for (int tt = 0; tt < 5; ++tt) {
        bf16x8 bk = *(const bf16x8*)(kbase + (size_t)(tt * 16 + col) * DP + kk);
        sc[tt] = MFMA16(bk, aq, sc[tt]);
      }
    }
    float mx = -1e30f;
#pragma unroll
    for (int tt = 0; tt < 5; ++tt)
#pragma unroll
      for (int r = 0; r < 4; ++r) {
        float v = sc[tt][r];
        if (tt == 4 && r >= 1 && quad == 3) v = -1e30f;
        sc[tt][r] = v;
        mx = fmaxf(mx, v);
      }
    mx = fmaxf(mx, __shfl_xor(mx, 16));
    mx = fmaxf(mx, __shfl_xor(mx, 32));
    float sum = 0.f;
#pragma unroll
    for (int tt = 0; tt < 5; ++tt)
#pragma unroll
      for (int r = 0; r < 4; ++r) {
        float e = __expf(sc[tt][r] - mx);
        sc[tt][r] = e;
        sum += e;
      }
    sum += __shfl_xor(sum, 16);
    sum += __shfl_xor(sum, 32);
    float rl = 1.f / sum;

    bf16x4 pb[5];
#pragma unroll
    for (int tt = 0; tt < 5; ++tt) {
      pb[tt][0] = f2bf(sc[tt][0] * rl);
      pb[tt][1] = f2bf(sc[tt][1] * rl);
      pb[tt][2] = f2bf(sc[tt][2] * rl);
      pb[tt][3] = f2bf(sc[tt][3] * rl);
    }

    f32x4 av[5] = {};
#pragma unroll
    for (int tt = 0; tt < 5; ++tt) {
#pragma unroll
      for (int dt = 0; dt < 5; ++dt) {
        bf16x4 va = *(const bf16x4*)(vbase + (size_t)(dt * 16 + col) * DP + tt * 16 + quad * 4);
        av[dt] = MFMAK16(va, pb[tt], av[dt]);
      }
    }

    size_t srow = (size_t)(s0 + wm * 64 + sg * 16 + col) * 640 + head * 80;
#pragma unroll
    for (int dt = 0; dt < 5; ++dt) {
      bf16x4 o;
      o[0] = f2bf(av[dt][0]);
      o[1] = f2bf(av[dt][1]);
      o[2] = f2bf(av[dt][2]);
      o[3] = f2bf(av[dt][3]);
      *(bf16x4*)(qws + srow + dt * 16 + quad * 4) = o;
    }
  }
}

// ================= K4: out projection, BN=64, BK=64 swizzled, 512-thread ==========
// 1D grid 5120, XCD-clustered: xcd = f&7 owns 64 contiguous s-tiles x 10 c-tiles
// (av re-reads are same-XCD L2 hits per R20 -> BN=64 no longer costs HBM traffic).
// LDS 48 KB -> 3 blocks/CU (~57% occupancy); per-wave 64s x 16c, acc[4].
__global__ __launch_bounds__(512) void k_o(const short* __restrict__ av,
                                           const short* __restrict__ woT,
                                           const float* __restrict__ bo,
                                           const float* __restrict__ hs,
                                           float* __restrict__ out) {
  int f = blockIdx.x;
  int xcd = f & 7;
  int i = f >> 3;                 // 0..639
  int st = xcd * 64 + i / 10;
  int ct = i - (i / 10) * 10;
  int s0 = st * 128;
  int c0 = ct * 64;
  __shared__ short sA[2 * 128 * 64];  // 32 KB
  __shared__ short sB[2 * 64 * 64];   // 16 KB
  int w = threadIdx.x >> 6, lane = threadIdx.x & 63;
  int col = lane & 15, quad = lane >> 4;
  int wm = w & 1, wn = w >> 1;  // wm: s-half (64), wn: c-slice (16) 0..3

  int lrow = lane >> 3;
  int ss = (lane & 7) ^ lrow;
  const short* gA = av + (size_t)(s0 + w * 8 + lrow) * 640 + ss * 8;
  const short* gB = woT + (size_t)(c0 + w * 8 + lrow) * 640 + ss * 8;

  auto stage = [&](int kt, int bi) {
#pragma unroll
    for (int r = 0; r < 2; ++r)
      gload16(gA + (size_t)r * 64 * 640 + kt * 64, sA + bi * 8192 + (r * 64 + w * 8) * 64);
    gload16(gB + kt * 64, sB + bi * 4096 + (w * 8) * 64);
  };

  f32x4 acc[4] = {};
  stage(0, 0);
  for (int kt = 0; kt < 10; ++kt) {
    int bi = kt & 1;
    if (kt < 9) {
      stage(kt + 1, bi ^ 1);
      asm volatile("s_waitcnt vmcnt(3)" ::: "memory");  // tile kt's 3 done
    } else {
      asm volatile("s_waitcnt vmcnt(0)" ::: "memory");
    }
    __builtin_amdgcn_s_barrier();  // all waves staged tile kt
    bf16x8 a[2][4], bb[2];
#pragma unroll
    for (int kh = 0; kh < 2; ++kh) {
      int so = ((kh * 4 + quad) ^ (col & 7)) * 8;
#pragma unroll
      for (int mt = 0; mt < 4; ++mt)
        a[kh][mt] = *(const bf16x8*)(sA + bi * 8192 + (wm * 64 + mt * 16 + col) * 64 + so);
      bb[kh] = *(const bf16x8*)(sB + bi * 4096 + (wn * 16 + col) * 64 + so);
    }
    asm volatile("s_waitcnt lgkmcnt(0)" ::: "memory");
    __builtin_amdgcn_sched_barrier(0);  // rule #18
    __builtin_amdgcn_s_barrier();       // reads done -> re-stage ok
#pragma unroll
    for (int kh = 0; kh < 2; ++kh)
#pragma unroll
      for (int mt = 0; mt < 4; ++mt)
        acc[mt] = MFMA16(a[kh][mt], bb[kh], acc[mt]);
  }
  // epilogue: C rows = s -> lane holds 4 consecutive s => float4 on hs/out
  int b = s0 >> 12;
  int sin = s0 & 4095;
  size_t obase = (size_t)b * CC * SS;
#pragma unroll
  for (int mt = 0; mt < 4; ++mt) {
    int s = sin + wm * 64 + mt * 16 + quad * 4;
    int c = c0 + wn * 16 + col;
    size_t idx = obase + (size_t)c * SS + s;
    float bc = bo[c];
    float4 h = *(const float4*)(hs + idx);
    float4 o;
    o.x = acc[mt][0] + bc + h.x;
    o.y = acc[mt][1] + bc + h.y;
    o.z = acc[mt][2] + bc + h.z;
    o.w = acc[mt][3] + bc + h.w;
    *(float4*)(out + idx) = o;
  }
}

// ================= host =================
extern "C" void kernel_launch(void* const* d_in, const int* in_sizes, int n_in,
                              void* d_out, int out_size, void* d_ws, size_t ws_size,
                              hipStream_t stream) {
  const float* hs  = (const float*)d_in[0];
  const float* enc = (const float*)d_in[1];
  const float* lnw = (const float*)d_in[2];
  const float* lnb = (const float*)d_in[3];
  const float* wq  = (const float*)d_in[4];
  const float* wk  = (const float*)d_in[5];
  const float* wv  = (const float*)d_in[6];
  const float* wo  = (const float*)d_in[7];
  const float* bo  = (const float*)d_in[8];
  float* out = (float*)d_out;

  char* ws = (char*)d_ws;
  short* wqT = (short*)(ws + 0);
  short* woT = (short*)(ws + 819200);
  short* kb  = (short*)(ws + 1638400);
  short* vb  = (short*)(ws + 3604480);
  short* xn  = (short*)(ws + 5570560);
  short* q   = (short*)(ws + 89456640);
  short* encb = q;  // scratch inside av region, consumed before k_qa writes av
  short* wkT = (short*)(ws + 89456640 + 1966080);
  short* wvT = (short*)(ws + 89456640 + 2949120);

  (void)hipMemsetAsync(ws + 1638400, 0, 3932160, stream);  // kb/vb pad regions

  k_wt<<<dim3(10, 12, 4), 256, 0, stream>>>(wq, wo, wk, wv, wqT, woT, wkT, wvT);
  k_enc<<<480, 256, 0, stream>>>(enc, encb);
  k_kv2<<<dim3(10, 10), 256, 0, stream>>>(encb, wkT, wvT, kb, vb);
  k_ln<<<1024, 512, 0, stream>>>(hs, lnw, lnb, xn);
  k_qa<<<2048, 256, 0, stream>>>(xn, wqT, kb, vb, q);
  k_o<<<5120, 512, 0, stream>>>(q, woT, bo, hs, out);
}

// Round 23
// 328.012 us; speedup vs baseline: 1.0229x; 1.0229x over previous
//
#include <hip/hip_runtime.h>

typedef short bf16x8 __attribute__((ext_vector_type(8)));
typedef short bf16x4 __attribute__((ext_vector_type(4)));
typedef float f32x4 __attribute__((ext_vector_type(4)));

#define MFMA16(a, b, c) __builtin_amdgcn_mfma_f32_16x16x32_bf16(a, b, c, 0, 0, 0)

// K=16 bf16 mfma: device pass has the builtin; host pass only needs to parse.
#if defined(__HIP_DEVICE_COMPILE__)
#define MFMAK16(a, b, c) __builtin_amdgcn_mfma_f32_16x16x16bf16_1k(a, b, c, 0, 0, 0)
#else
#define MFMAK16(a, b, c) (c)
#endif

__device__ __forceinline__ short f2bf(float x) {
  unsigned u = __builtin_bit_cast(unsigned, x);
  u += 0x7fffu + ((u >> 16) & 1u);
  return (short)(u >> 16);
}

// async global->LDS, 16B per lane; LDS dest must be wave-uniform base (HW adds lane*16)
__device__ __forceinline__ void gload16(const void* g, void* l) {
  __builtin_amdgcn_global_load_lds((const __attribute__((address_space(1))) void*)g,
                                   (__attribute__((address_space(3))) void*)l, 16, 0, 0);
}

// ---- problem constants ----
#define BB 16
#define SS 4096
#define CC 640
#define TT 77
#define NHH 8
#define HDD 80
#define DP 96
#define MM (BB * SS)

// ================= K0a: weight transpose + bf16 convert (wq, wo, wk, wv) =========
__global__ __launch_bounds__(256) void k_wt(const float* __restrict__ wq,
                                            const float* __restrict__ wo,
                                            const float* __restrict__ wk,
                                            const float* __restrict__ wv,
                                            short* __restrict__ wqT,
                                            short* __restrict__ woT,
                                            short* __restrict__ wkT,
                                            short* __restrict__ wvT) {
  int z = blockIdx.z;
  const float* src = (z == 0) ? wq : (z == 1) ? wo : (z == 2) ? wk : wv;
  short* dst = (z == 0) ? wqT : (z == 1) ? woT : (z == 2) ? wkT : wvT;
  int R = (z < 2) ? 640 : 768;
  int r0 = blockIdx.y * 64;
  if (r0 >= R) return;
  int o0 = blockIdx.x * 64;
  __shared__ float t[64][65];
  int tx = threadIdx.x & 63, ty = threadIdx.x >> 6;
#pragma unroll
  for (int it = 0; it < 16; ++it) {
    int rr = it * 4 + ty;
    t[tx][rr] = src[(size_t)(r0 + rr) * 640 + o0 + tx];
  }
  __syncthreads();
#pragma unroll
  for (int it = 0; it < 16; ++it) {
    int orow = it * 4 + ty;
    dst[(size_t)(o0 + orow) * R + r0 + tx] = f2bf(t[orow][tx]);
  }
}

// ================= K0b: enc -> bf16 [1280][768] (rows >=1232 zeroed) ===========
__global__ __launch_bounds__(256) void k_enc(const float* __restrict__ enc,
                                             short* __restrict__ encb) {
  int idx = (blockIdx.x * 256 + threadIdx.x) * 8;  // 8 shorts, same row (768%8==0)
  int row = idx / 768;
  bf16x8 o = {};
  if (row < 1232) {
    const float* p = enc + (size_t)row * 768 + (idx % 768);
    float4 a0 = *(const float4*)p;
    float4 a1 = *(const float4*)(p + 4);
    o[0] = f2bf(a0.x); o[1] = f2bf(a0.y); o[2] = f2bf(a0.z); o[3] = f2bf(a0.w);
    o[4] = f2bf(a1.x); o[5] = f2bf(a1.y); o[6] = f2bf(a1.z); o[7] = f2bf(a1.w);
  }
  *(bf16x8*)(encb + idx) = o;
}

// ================= K0c: K/V projection as m97-style GEMM =================
// M = 1280 (16b x 77t padded), N = 1280 (K | V), K = 768.
__global__ __launch_bounds__(256) void k_kv2(const short* __restrict__ encb,
                                             const short* __restrict__ wkT,
                                             const short* __restrict__ wvT,
                                             short* __restrict__ kb,
                                             short* __restrict__ vb) {
  int n0 = blockIdx.x * 128;
  int m0 = blockIdx.y * 128;
  __shared__ short sA[2 * 128 * 32];
  __shared__ short sB[2 * 128 * 32];
  int w = threadIdx.x >> 6, lane = threadIdx.x & 63;
  int col = lane & 15, quad = lane >> 4;
  int wm = w & 1, wn = w >> 1;
  int ldrow = lane >> 2;
  int ldoff = (lane & 3) * 8;
  bool isV = (n0 >= 640);
  const short* wsrc = isV ? (wvT + (size_t)(n0 - 640) * 768) : (wkT + (size_t)n0 * 768);
  const short* gA0 = encb + (size_t)(m0 + w * 32 + ldrow) * 768 + ldoff;
  const short* gA1 = gA0 + 16 * 768;
  const short* gB0 = wsrc + (size_t)(w * 32 + ldrow) * 768 + ldoff;
  const short* gB1 = gB0 + 16 * 768;
  short* lA0 = sA + (w * 32) * 32;  // wave-uniform
  short* lA1 = lA0 + 16 * 32;
  short* lB0 = sB + (w * 32) * 32;
  short* lB1 = lB0 + 16 * 32;
  f32x4 acc[4][4] = {};
  gload16(gA0, lA0);
  gload16(gA1, lA1);
  gload16(gB0, lB0);
  gload16(gB1, lB1);
  for (int k0 = 0; k0 < 768; k0 += 32) {
    int cur = ((k0 >> 5) & 1) << 12;  // 0 or 4096 shorts
    if (k0 + 32 < 768) {
      int nxt = cur ^ 4096;
      gload16(gA0 + k0 + 32, lA0 + nxt);
      gload16(gA1 + k0 + 32, lA1 + nxt);
      gload16(gB0 + k0 + 32, lB0 + nxt);
      gload16(gB1 + k0 + 32, lB1 + nxt);
      asm volatile("s_waitcnt vmcnt(4)" ::: "memory");
    } else {
      asm volatile("s_waitcnt vmcnt(0)" ::: "memory");
    }
    __builtin_amdgcn_s_barrier();
    bf16x8 a[4], bb[4];
#pragma unroll
    for (int mt = 0; mt < 4; ++mt)
      a[mt] = *(const bf16x8*)(sA + cur + (wm * 64 + mt * 16 + col) * 32 + quad * 8);
#pragma unroll
    for (int nt = 0; nt < 4; ++nt)
      bb[nt] = *(const bf16x8*)(sB + cur + (wn * 64 + nt * 16 + col) * 32 + quad * 8);
    asm volatile("s_waitcnt lgkmcnt(0)" ::: "memory");
    __builtin_amdgcn_sched_barrier(0);
    __builtin_amdgcn_s_barrier();
#pragma unroll
    for (int mt = 0; mt < 4; ++mt)
#pragma unroll
      for (int nt = 0; nt < 4; ++nt)
        acc[mt][nt] = MFMA16(a[mt], bb[nt], acc[mt][nt]);
  }
  float scale = isV ? 1.f : 0.11180339887498949f;
#pragma unroll
  for (int mt = 0; mt < 4; ++mt)
#pragma unroll
    for (int nt = 0; nt < 4; ++nt) {
      int i = n0 + wn * 64 + nt * 16 + col;      // global 0..1279
      int j = isV ? (i - 640) : i;               // 0..639
      int h = j / 80, d = j % 80;
#pragma unroll
      for (int r = 0; r < 4; ++r) {
        int m = m0 + wm * 64 + mt * 16 + quad * 4 + r;
        if (m >= 1232) continue;
        int b = m / 77;
        int t = m - b * 77;
        float v = acc[mt][nt][r] * scale;
        if (isV)
          vb[(((size_t)(b * NHH + h) * 80 + d) * DP) + t] = f2bf(v);
        else
          kb[(((size_t)(b * NHH + h) * 80 + t) * DP) + d] = f2bf(v);
      }
    }
}

// ================= K1: fused LN, ONE-PASS (hs cached in f32 registers) =========
__global__ __launch_bounds__(512) void k_ln(const float* __restrict__ hs,
                                            const float* __restrict__ lnw,
                                            const float* __restrict__ lnb,
                                            short* __restrict__ xn) {
  int b = blockIdx.x >> 6;
  int s0 = (blockIdx.x & 63) * 64;
  int t = threadIdx.x;
  int sq = t & 15, cg = t >> 4;  // sq: s-quad, cg: c-group 0..31
  int s4 = sq * 4;
  const float* base = hs + (size_t)b * CC * SS + s0;
  f32x4 v[20];
  f32x4 sum = {}, sqs = {};
#pragma unroll
  for (int m = 0; m < 20; ++m) {
    int c = cg + m * 32;
    v[m] = *(const f32x4*)(base + (size_t)c * SS + s4);
    sum += v[m];
    sqs += v[m] * v[m];
  }
  __shared__ f32x4 redS[32][16];
  __shared__ f32x4 redQ[32][16];
  __shared__ float smu[64], srs[64];
  redS[cg][sq] = sum;
  redQ[cg][sq] = sqs;
  __syncthreads();
  if (t < 64) {
    int q = t >> 2, j = t & 3;
    float s = 0.f, qq = 0.f;
#pragma unroll
    for (int g = 0; g < 32; ++g) { s += redS[g][q][j]; qq += redQ[g][q][j]; }
    float mu = s * (1.f / 640.f);
    float var = qq * (1.f / 640.f) - mu * mu;
    smu[t] = mu;
    srs[t] = rsqrtf(var + 1e-6f);
  }
  __syncthreads();
  float mu[4], rs[4];
#pragma unroll
  for (int j = 0; j < 4; ++j) { mu[j] = smu[s4 + j]; rs[j] = srs[s4 + j]; }
  __shared__ short tq[64][80];  // 160B rows, 16B-aligned
  short* xrow = xn + (size_t)(b * SS + s0) * 640;
#pragma unroll
  for (int ch = 0; ch < 10; ++ch) {  // full unroll: v[] indices stay compile-time
    int c0 = ch * 64;
    if (ch) __syncthreads();
#pragma unroll
    for (int h = 0; h < 2; ++h) {
      int m = ch * 2 + h;
      int c = c0 + h * 32 + cg;
      float w = lnw[c], bb = lnb[c];
#pragma unroll
      for (int j = 0; j < 4; ++j)
        tq[s4 + j][h * 32 + cg] = f2bf((v[m][j] - mu[j]) * rs[j] * w + bb);
    }
    __syncthreads();
    {
      int s = t >> 3, g = t & 7;  // 512 thr cover 64 rows x 64 c in one shot
      uint4 x = *(const uint4*)&tq[s][g * 8];
      *(uint4*)(xrow + (size_t)s * 640 + c0 + g * 8) = x;
    }
  }
}

// ================= K2+K3 fused: Q projection + attention (R14 body) =====
// 1D grid 2048, XCD-clustered mapping (R19/R20-verified: FETCH 171->55 MB):
// xcd = f&7 owns 64 contiguous s-tiles x 4 pairs -> siblings share one XCD L2.
__global__ __launch_bounds__(256) void k_qa(const short* __restrict__ xn,
                                            const short* __restrict__ wqT,
                                            const short* __restrict__ kb,
                                            const short* __restrict__ vb,
                                            short* __restrict__ qws) {
  int f = blockIdx.x;
  int xcd = f & 7;
  int i = f >> 3;                 // 0..255
  int s0 = (xcd * 64 + (i >> 2)) * 128;
  int pair = i & 3;
  int b = s0 >> 12;
  int t = threadIdx.x;
  int w = t >> 6, lane = t & 63;
  int col = lane & 15, quad = lane >> 4;
  int wm = w & 1, wh = w >> 1;
  int head = pair * 2 + wh;

  __shared__ short smem[4 * 64 * 104];  // 26624 shorts = 53248 B
  short* lA = smem;           // [2][128][32]
  short* lB = smem + 8192;    // [2][160][32]

  int ldrow = lane >> 2, ldoff = (lane & 3) * 8;
  const short* gA = xn + (size_t)(s0 + w * 32 + ldrow) * 640 + ldoff;
  int browbase = (w < 2) ? w * 48 : 96 + (w - 2) * 32;
  const short* gB = wqT + (size_t)(pair * 160 + browbase + ldrow) * 640 + ldoff;
  short* lAw = lA + (w * 32) * 32;
  short* lBw = lB + browbase * 32;

  f32x4 acc[4][5] = {};
  gload16(gA, lAw);
  gload16(gA + 16 * 640, lAw + 16 * 32);
  if (w < 2) {
    gload16(gB, lBw);
    gload16(gB + 16 * 640, lBw + 16 * 32);
    gload16(gB + 32 * 640, lBw + 32 * 32);
  } else {
    gload16(gB, lBw);
    gload16(gB + 16 * 640, lBw + 16 * 32);
  }
  for (int k0 = 0; k0 < 640; k0 += 32) {
    int coA = (k0 & 32) * 128;
    int coB = (k0 & 32) * 160;
    if (k0 + 32 < 640) {
      int nxA = coA ^ 4096;
      int nxB = coB ^ 5120;
      gload16(gA + k0 + 32, lAw + nxA);
      gload16(gA + 16 * 640 + k0 + 32, lAw + nxA + 16 * 32);
      if (w < 2) {
        gload16(gB + k0 + 32, lBw + nxB);
        gload16(gB + 16 * 640 + k0 + 32, lBw + nxB + 16 * 32);
        gload16(gB + 32 * 640 + k0 + 32, lBw + nxB + 32 * 32);
        asm volatile("s_waitcnt vmcnt(5)" ::: "memory");
      } else {
        gload16(gB + k0 + 32, lBw + nxB);
        gload16(gB + 16 * 640 + k0 + 32, lBw + nxB + 16 * 32);
        asm volatile("s_waitcnt vmcnt(4)" ::: "memory");
      }
    } else {
      asm volatile("s_waitcnt vmcnt(0)" ::: "memory");
    }
    __builtin_amdgcn_s_barrier();
    bf16x8 a[4], bb[5];
#pragma unroll
    for (int mt = 0; mt < 4; ++mt)
      a[mt] = *(const bf16x8*)(lA + coA + (wm * 64 + mt * 16 + col) * 32 + quad * 8);
#pragma unroll
    for (int nt = 0; nt < 5; ++nt)
      bb[nt] = *(const bf16x8*)(lB + coB + (wh * 80 + nt * 16 + col) * 32 + quad * 8);
    asm volatile("s_waitcnt lgkmcnt(0)" ::: "memory");
    __builtin_amdgcn_sched_barrier(0);
    __builtin_amdgcn_s_barrier();
#pragma unroll
    for (int mt = 0; mt < 4; ++mt)
#pragma unroll
      for (int nt = 0; nt < 5; ++nt)
        acc[mt][nt] = MFMA16(a[mt], bb[nt], acc[mt][nt]);
  }

  short* ql = smem + w * 6656;
  {
    uint4 z = {0u, 0u, 0u, 0u};
    *(uint4*)&ql[lane * 104 + 80] = z;
    *(uint4*)&ql[lane * 104 + 88] = z;
  }
#pragma unroll
  for (int mt = 0; mt < 4; ++mt)
#pragma unroll
    for (int nt = 0; nt < 5; ++nt)
#pragma unroll
      for (int r = 0; r < 4; ++r)
        ql[(mt * 16 + quad * 4 + r) * 104 + nt * 16 + col] = f2bf(acc[mt][nt][r]);

  const short* kbase = kb + (size_t)(b * NHH + head) * 80 * DP;
  const short* vbase = vb + (size_t)(b * NHH + head) * 80 * DP;
  int kq = quad * 8;
#pragma unroll 1
  for (int sg = 0; sg < 4; ++sg) {
    f32x4 sc[5] = {};
#pragma unroll
    for (int ks = 0; ks < 3; ++ks) {
      int kk = ks * 32 + kq;
      bf16x8 aq = *(const bf16x8*)&ql[(sg * 16 + col) * 104 + kk];
#pragma unroll
      for (int tt = 0; tt < 5; ++tt) {
        bf16x8 bk = *(const bf16x8*)(kbase + (size_t)(tt * 16 + col) * DP + kk);
        sc[tt] = MFMA16(bk, aq, sc[tt]);
      }
    }
    float mx = -1e30f;
#pragma unroll
    for (int tt = 0; tt < 5; ++tt)
#pragma unroll
      for (int r = 0; r < 4; ++r) {
        float v = sc[tt][r];
        if (tt == 4 && r >= 1 && quad == 3) v = -1e30f;
        sc[tt][r] = v;
        mx = fmaxf(mx, v);
      }
    mx = fmaxf(mx, __shfl_xor(mx, 16));
    mx = fmaxf(mx, __shfl_xor(mx, 32));
    float sum = 0.f;
#pragma unroll
    for (int tt = 0; tt < 5; ++tt)
#pragma unroll
      for (int r = 0; r < 4; ++r) {
        float e = __expf(sc[tt][r] - mx);
        sc[tt][r] = e;
        sum += e;
      }
    sum += __shfl_xor(sum, 16);
    sum += __shfl_xor(sum, 32);
    float rl = 1.f / sum;

    bf16x4 pb[5];
#pragma unroll
    for (int tt = 0; tt < 5; ++tt) {
      pb[tt][0] = f2bf(sc[tt][0] * rl);
      pb[tt][1] = f2bf(sc[tt][1] * rl);
      pb[tt][2] = f2bf(sc[tt][2] * rl);
      pb[tt][3] = f2bf(sc[tt][3] * rl);
    }

    f32x4 av[5] = {};
#pragma unroll
    for (int tt = 0; tt < 5; ++tt) {
#pragma unroll
      for (int dt = 0; dt < 5; ++dt) {
        bf16x4 va = *(const bf16x4*)(vbase + (size_t)(dt * 16 + col) * DP + tt * 16 + quad * 4);
        av[dt] = MFMAK16(va, pb[tt], av[dt]);
      }
    }

    size_t srow = (size_t)(s0 + wm * 64 + sg * 16 + col) * 640 + head * 80;
#pragma unroll
    for (int dt = 0; dt < 5; ++dt) {
      bf16x4 o;
      o[0] = f2bf(av[dt][0]);
      o[1] = f2bf(av[dt][1]);
      o[2] = f2bf(av[dt][2]);
      o[3] = f2bf(av[dt][3]);
      *(bf16x4*)(qws + srow + dt * 16 + quad * 4) = o;
    }
  }
}

// ================= K4: out projection, BK=64 swizzled, 512-thread =================
// 1D grid 2560, XCD-clustered: xcd = f&7 owns 64 contiguous s-tiles x 5 c-tiles
// (R20-verified: FETCH 312->143 MB).
__global__ __launch_bounds__(512) void k_o(const short* __restrict__ av,
                                           const short* __restrict__ woT,
                                           const float* __restrict__ bo,
                                           const float* __restrict__ hs,
                                           float* __restrict__ out) {
  int f = blockIdx.x;
  int xcd = f & 7;
  int i = f >> 3;                 // 0..319
  int st = xcd * 64 + i / 5;
  int ct = i - (i / 5) * 5;
  int s0 = st * 128;
  int c0 = ct * 128;
  __shared__ short sA[2 * 128 * 64];  // 32 KB
  __shared__ short sB[2 * 128 * 64];  // 32 KB
  int w = threadIdx.x >> 6, lane = threadIdx.x & 63;
  int col = lane & 15, quad = lane >> 4;
  int wm = w & 1, wn = w >> 1;  // wm: s-half (64), wn: c-slice (32)

  int lrow = lane >> 3;
  int ss = (lane & 7) ^ lrow;
  const short* gA = av + (size_t)(s0 + w * 8 + lrow) * 640 + ss * 8;
  const short* gB = woT + (size_t)(c0 + w * 8 + lrow) * 640 + ss * 8;

  auto stage = [&](int kt, int bi) {
#pragma unroll
    for (int r = 0; r < 2; ++r) {
      gload16(gA + (size_t)r * 64 * 640 + kt * 64, sA + bi * 8192 + (r * 64 + w * 8) * 64);
      gload16(gB + (size_t)r * 64 * 640 + kt * 64, sB + bi * 8192 + (r * 64 + w * 8) * 64);
    }
  };

  f32x4 acc[4][2] = {};
  stage(0, 0);
  for (int kt = 0; kt < 10; ++kt) {
    int bi = kt & 1;
    if (kt < 9) {
      stage(kt + 1, bi ^ 1);
      asm volatile("s_waitcnt vmcnt(4)" ::: "memory");  // tile kt's 4 done
    } else {
      asm volatile("s_waitcnt vmcnt(0)" ::: "memory");
    }
    __builtin_amdgcn_s_barrier();  // all waves staged tile kt
    bf16x8 a[2][4], bb[2][2];
#pragma unroll
    for (int kh = 0; kh < 2; ++kh) {
      int so = ((kh * 4 + quad) ^ (col & 7)) * 8;
#pragma unroll
      for (int mt = 0; mt < 4; ++mt)
        a[kh][mt] = *(const bf16x8*)(sA + bi * 8192 + (wm * 64 + mt * 16 + col) * 64 + so);
#pragma unroll
      for (int nt = 0; nt < 2; ++nt)
        bb[kh][nt] = *(const bf16x8*)(sB + bi * 8192 + (wn * 32 + nt * 16 + col) * 64 + so);
    }
    asm volatile("s_waitcnt lgkmcnt(0)" ::: "memory");
    __builtin_amdgcn_sched_barrier(0);  // rule #18
    __builtin_amdgcn_s_barrier();       // reads done -> re-stage ok
#pragma unroll
    for (int kh = 0; kh < 2; ++kh)
#pragma unroll
      for (int mt = 0; mt < 4; ++mt)
#pragma unroll
        for (int nt = 0; nt < 2; ++nt)
          acc[mt][nt] = MFMA16(a[kh][mt], bb[kh][nt], acc[mt][nt]);
  }
  // epilogue: C rows = s -> lane holds 4 consecutive s => float4 on hs/out
  int b = s0 >> 12;
  int sin = s0 & 4095;
  size_t obase = (size_t)b * CC * SS;
#pragma unroll
  for (int mt = 0; mt < 4; ++mt)
#pragma unroll
    for (int nt = 0; nt < 2; ++nt) {
      int s = sin + wm * 64 + mt * 16 + quad * 4;
      int c = c0 + wn * 32 + nt * 16 + col;
      size_t idx = obase + (size_t)c * SS + s;
      float bc = bo[c];
      float4 h = *(const float4*)(hs + idx);
      float4 o;
      o.x = acc[mt][nt][0] + bc + h.x;
      o.y = acc[mt][nt][1] + bc + h.y;
      o.z = acc[mt][nt][2] + bc + h.z;
      o.w = acc[mt][nt][3] + bc + h.w;
      *(float4*)(out + idx) = o;
    }
}

// ================= host =================
extern "C" void kernel_launch(void* const* d_in, const int* in_sizes, int n_in,
                              void* d_out, int out_size, void* d_ws, size_t ws_size,
                              hipStream_t stream) {
  const float* hs  = (const float*)d_in[0];
  const float* enc = (const float*)d_in[1];
  const float* lnw = (const float*)d_in[2];
  const float* lnb = (const float*)d_in[3];
  const float* wq  = (const float*)d_in[4];
  const float* wk  = (const float*)d_in[5];
  const float* wv  = (const float*)d_in[6];
  const float* wo  = (const float*)d_in[7];
  const float* bo  = (const float*)d_in[8];
  float* out = (float*)d_out;

  char* ws = (char*)d_ws;
  short* wqT = (short*)(ws + 0);
  short* woT = (short*)(ws + 819200);
  short* kb  = (short*)(ws + 1638400);
  short* vb  = (short*)(ws + 3604480);
  short* xn  = (short*)(ws + 5570560);
  short* q   = (short*)(ws + 89456640);
  short* encb = q;  // scratch inside av region, consumed before k_qa writes av
  short* wkT = (short*)(ws + 89456640 + 1966080);
  short* wvT = (short*)(ws + 89456640 + 2949120);

  (void)hipMemsetAsync(ws + 1638400, 0, 3932160, stream);  // kb/vb pad regions

  k_wt<<<dim3(10, 12, 4), 256, 0, stream>>>(wq, wo, wk, wv, wqT, woT, wkT, wvT);
  k_enc<<<480, 256, 0, stream>>>(enc, encb);
  k_kv2<<<dim3(10, 10), 256, 0, stream>>>(encb, wkT, wvT, kb, vb);
  k_ln<<<1024, 512, 0, stream>>>(hs, lnw, lnb, xn);
  k_qa<<<2048, 256, 0, stream>>>(xn, wqT, kb, vb, q);
  k_o<<<2560, 512, 0, stream>>>(q, woT, bo, hs, out);
}